// Round 13
// baseline (240.343 us; speedup 1.0000x reference)
//
#include <hip/hip_runtime.h>
#include <hip/hip_bf16.h>

#define B_SZ 16384
#define N_SZ 64
#define D_SZ 64
#define H_SZ 128
#define R_PB 3              // rows per block (LDS ~31.2 KB -> 5 blocks/CU)
#define ARS 68              // A row stride, bf16 elems (136 B; 2-way banks = free)
#define CRS 264             // comb row stride, bf16 elems (payload 256 elems)
#define GRID ((B_SZ + R_PB - 1) / R_PB)

typedef short bf16x8 __attribute__((ext_vector_type(8)));
typedef float f32x4  __attribute__((ext_vector_type(4)));
typedef float f32x2  __attribute__((ext_vector_type(2)));

#define INV2PI 0.15915494309189535f
#define TWO_PI 6.283185307179586f

__device__ __forceinline__ float bits2f(unsigned short r){union{unsigned i;float f;}c;c.i=((unsigned)r)<<16;return c.f;}
__device__ __forceinline__ unsigned f2bfbits(float f){
    __hip_bfloat16 h = __float2bfloat16(f);           // RNE
    unsigned short u;
    __builtin_memcpy(&u, &h, 2);
    return (unsigned)u;
}
__device__ __forceinline__ unsigned pack2bf(float a, float b){   // v_cvt_pk_bf16_f32
    __hip_bfloat162 h = __float22bfloat162_rn(make_float2(a, b));
    unsigned r;
    __builtin_memcpy(&r, &h, 4);
    return r;
}
__device__ __forceinline__ float bf2f(__hip_bfloat16 x) { return __bfloat162float(x); }

template<int CTRL>
__device__ __forceinline__ float dpp_add(float v){
    int t = __builtin_amdgcn_mov_dpp(__builtin_bit_cast(int, v), CTRL, 0xf, 0xf, true);
    return v + __builtin_bit_cast(float, t);
}

// cos(2*pi*v): v is pre-scaled by 1/2pi -> v_fract + v_cos (2 inst) instead of full __cosf
__device__ __forceinline__ float cos_rev(float v){
#if __has_builtin(__builtin_amdgcn_cosf)
    return __builtin_amdgcn_cosf(v - floorf(v));
#else
    return __cosf(v * TWO_PI);
#endif
}

__device__ __forceinline__ float tanh_fast(float x){
    float e = exp2f(x * 2.8853900817779268f);          // 2*log2(e) folded into one mul
    return 1.0f - __fdividef(2.0f, e + 1.0f);          // exact at +-inf saturation
}

// FMODE 0: bf16 tensors, 1: f32 tensors
template<int FMODE>
__device__ __forceinline__ float LD(const void* p, int i) {
    if constexpr (FMODE == 0) return bf2f(((const __hip_bfloat16*)p)[i]);
    else                      return ((const float*)p)[i];
}

// mask modes: 0 = int32, 1 = int8/bool, 2 = bf16, 3 = f32
__device__ __forceinline__ float mval(const void* p, int i, int mode) {
    if (mode == 0) return ((const int*)p)[i]            ? 1.0f : 0.0f;
    if (mode == 1) return ((const unsigned char*)p)[i]  ? 1.0f : 0.0f;
    if (mode == 2) return ((const unsigned short*)p)[i] ? 1.0f : 0.0f;
    return ((const unsigned int*)p)[i]                  ? 1.0f : 0.0f;
}

// dt_node strictly positive: bf16 words never set bit15; f32 low-mantissa words do (w.p. 1-2^-32)
__device__ __forceinline__ int detect_f32(const void* p) {
    const uint4* q = (const uint4*)p;
    unsigned o = 0;
    #pragma unroll
    for (int i = 0; i < 8; ++i) { uint4 v = q[i]; o |= v.x | v.y | v.z | v.w; }
    return (o & 0x80008000u) ? 1 : 0;
}

// 0/1-valued mask, 128 head bytes (see earlier rounds)
__device__ __forceinline__ int detect_mask_mode(const void* p) {
    const uint4* q = (const uint4*)p;
    unsigned oa = 0, ofe = 0;
    #pragma unroll
    for (int i = 0; i < 8; ++i) {
        uint4 v = q[i];
        unsigned w = v.x | v.y | v.z | v.w;
        oa  |= w;
        ofe |= (v.x & 0xFEFEFEFEu) | (v.y & 0xFEFEFEFEu) | (v.z & 0xFEFEFEFEu) | (v.w & 0xFEFEFEFEu);
    }
    if ((oa & 0xFFFFFF00u) == 0) return 0;   // int32 0/1
    if (ofe == 0)                return 1;   // bool/int8
    if (oa & 0x000000FEu)        return 2;   // bf16
    return 3;                                // f32
}

// ---------------- prep: W1/W2 -> MFMA B-fragment layout in d_ws (16 KB), grid=4 ----------------
__global__ void prep_kernel(const void* dt_node, const void* att_W1, const void* att_W2,
                            void* ws) {
    const int t     = blockIdx.x * 256 + threadIdx.x;
    const int fmode = detect_f32(dt_node);
    const int fi  = t >> 6, ln = t & 63;
    const int et  = fi >> 2, ks = fi & 3;
    const int m16 = ln & 15, qd = ln >> 4;
    const int col = et * 16 + m16;
    unsigned short s[8];
    #pragma unroll
    for (int j = 0; j < 8; ++j) {
        const int i = ks * 32 + qd * 8 + j;
        if (fmode == 0) {
            s[j] = (i < 64) ? ((const unsigned short*)att_W1)[i * D_SZ + col]
                            : ((const unsigned short*)att_W2)[(i - 64) * D_SZ + col];
        } else {
            const float v = (i < 64) ? ((const float*)att_W1)[i * D_SZ + col]
                                     : ((const float*)att_W2)[(i - 64) * D_SZ + col];
            s[j] = (unsigned short)f2bfbits(v);
        }
    }
    ((uint4*)ws)[t] = make_uint4(((unsigned)s[0]) | (((unsigned)s[1]) << 16),
                                 ((unsigned)s[2]) | (((unsigned)s[3]) << 16),
                                 ((unsigned)s[4]) | (((unsigned)s[5]) << 16),
                                 ((unsigned)s[6]) | (((unsigned)s[7]) << 16));
}

struct Smem {
    alignas(16) unsigned short A[R_PB * 65 * ARS];  // [row][n 0..63 | node=64][d] normalized bf16
    alignas(16) unsigned short comb[4 * CRS];       // rows 0..2 = [node|agg|hist]; row 3 zeroed
    alignas(16) float prm[4][D_SZ];                 // t2v_w/2pi | t2v_b/2pi | node_w | 2*node_b
    float att[R_PB][N_SZ];
    float cf[R_PB][N_SZ];                           // mask*leakyrelu(ts)/n_in (att-independent)
};

// one 16-channel chunk of a feature row; params from LDS (pre-scaled); 2-inst cos;
// norm reduced across the 4 chunk-threads (width-4 shfl). snb PRE-DOUBLED.
__device__ __forceinline__ void feat_row(float t, float dc,
                                         const float* sw, const float* sb,
                                         const float* snw, const float* snb,
                                         int c, unsigned short* dstA, unsigned short* dstC) {
    f32x2 fp[8]; float ss = 0.0f;
    #pragma unroll
    for (int g = 0; g < 8; ++g) {
        const f32x2 w  = *(const f32x2*)(sw  + 2 * g);
        const f32x2 b  = *(const f32x2*)(sb  + 2 * g);
        const f32x2 nw = *(const f32x2*)(snw + 2 * g);
        const f32x2 nb = *(const f32x2*)(snb + 2 * g);
        f32x2 v = w * t + b;                            // v_pk_fma_f32 (arg in revolutions)
        f32x2 cv;
        cv.x = (c == 0 && g == 0) ? v.x * TWO_PI : cos_rev(v.x);   // channel 0 linear
        cv.y = cos_rev(v.y);
        f32x2 f = cv + (nw * dc + nb);
        ss = fmaf(f.x, f.x, ss);
        ss = fmaf(f.y, f.y, ss);
        fp[g] = f;
    }
    ss += __shfl_xor(ss, 1, 4);
    ss += __shfl_xor(ss, 2, 4);
    const float inv = 1.0f / fmaxf(sqrtf(ss), 1e-12f);
    unsigned pk[8];
    #pragma unroll
    for (int g = 0; g < 8; ++g)
        pk[g] = pack2bf(fp[g].x * inv, fp[g].y * inv);  // v_cvt_pk_bf16_f32
    uint4 v0 = make_uint4(pk[0], pk[1], pk[2], pk[3]);
    uint4 v1 = make_uint4(pk[4], pk[5], pk[6], pk[7]);
    ((uint4*)dstA)[0] = v0; ((uint4*)dstA)[1] = v1;
    if (dstC) { ((uint4*)dstC)[0] = v0; ((uint4*)dstC)[1] = v1; }
}

template<int FMODE, bool USE_WS>
__device__ __forceinline__ void body(
    Smem& sm,
    const void* dt_node, const void* deg_node, const void* cc_node,
    const void* dt_neigh, const void* deg_neigh, const void* cc_neigh,
    const void* neigh_mask, const void* feature_hist,
    const void* t2v_w, const void* t2v_b, const void* node_w, const void* node_b,
    const void* att_W1, const void* att_W2, const void* att_v,
    const void* weight, void* out, const void* ws, int mmode, int b0, int tid)
{
    const int lane = tid & 63;
    const int wv   = tid >> 6;
    const int m16  = lane & 15;
    const int quad = lane >> 4;

    // ---- Phase 0: stage params into LDS; zero comb row 3 ----
    {
        const int arr = tid >> 6, ch = tid & 63;
        float v;
        if      (arr == 0) v = LD<FMODE>(t2v_w,  ch) * INV2PI;
        else if (arr == 1) v = LD<FMODE>(t2v_b,  ch) * INV2PI;
        else if (arr == 2) v = LD<FMODE>(node_w, ch);
        else               v = 2.0f * LD<FMODE>(node_b, ch);   // deg-bias + cc-bias folded
        sm.prm[arr][ch] = v;
        if (tid < 128) ((unsigned*)(sm.comb + 3 * CRS))[tid] = 0;   // dummy A-row for P5
    }
    __syncthreads();

    // ---- Phase 1: features. 780 tasks = (3 rows x 65 feat-rows) x 4 chunks ----
    {
        const int c = tid & 3, d0 = c * 16;
        const float* sw  = sm.prm[0] + d0;
        const float* sb  = sm.prm[1] + d0;
        const float* snw = sm.prm[2] + d0;
        const float* snb = sm.prm[3] + d0;

        #pragma unroll
        for (int it = 0; it < 4; ++it) {
            const int t = tid + it * 256;
            if (t < R_PB * 65 * 4) {
                const int f = t >> 2;
                if (f < R_PB * 64) {
                    const int row = f >> 6, n = f & 63;
                    const int gr  = min(b0 + row, B_SZ - 1);        // tail clamp
                    const int idx = gr * N_SZ + n;
                    const float tn  = fabsf(LD<FMODE>(dt_neigh, idx));
                    const float dcn = LD<FMODE>(deg_neigh, idx) + LD<FMODE>(cc_neigh, idx);
                    feat_row(tn, dcn, sw, sb, snw, snb, c,
                             sm.A + (row * 65 + n) * ARS + d0, nullptr);
                } else {
                    const int row = f - R_PB * 64;
                    const int gr  = min(b0 + row, B_SZ - 1);
                    const float tn = fabsf(LD<FMODE>(dt_node, gr));
                    const float dc = LD<FMODE>(deg_node, gr) + LD<FMODE>(cc_node, gr);
                    feat_row(tn, dc, sw, sb, snw, snb, c,
                             sm.A + (row * 65 + 64) * ARS + d0,
                             sm.comb + row * CRS + d0);
                }
            }
        }
    }
    __syncthreads();

    // ---- Phase 2: waves 0-2: S + att for row r = wv. Wave 3: coef + hist (att-independent) ----
    if (wv < R_PB) {
        const int r = wv;
        const unsigned short* An = sm.A + (r * 65 + 64) * ARS + quad * 8;
        const bf16x8 a0 = *(const bf16x8*)An;          // node k  0..31
        const bf16x8 a1 = *(const bf16x8*)(An + 32);   // node k 32..63
        const bf16x8* wfrag = (const bf16x8*)ws;

        f32x4  accN[4];
        bf16x8 w2f[4], w3f[4];
        float  ve[4];
        #pragma unroll
        for (int et = 0; et < 4; ++et) {
            bf16x8 w0, w1;
            if constexpr (USE_WS) {
                w0      = wfrag[(et * 4 + 0) * 64 + lane];
                w1      = wfrag[(et * 4 + 1) * 64 + lane];
                w2f[et] = wfrag[(et * 4 + 2) * 64 + lane];
                w3f[et] = wfrag[(et * 4 + 3) * 64 + lane];
            } else {
                const int col = et * 16 + m16;
                #pragma unroll
                for (int j = 0; j < 8; ++j) {
                    const int k0 = quad * 8 + j;
                    if constexpr (FMODE == 0) {
                        w0[j]      = (short)((const unsigned short*)att_W1)[k0 * D_SZ + col];
                        w1[j]      = (short)((const unsigned short*)att_W1)[(k0 + 32) * D_SZ + col];
                        w2f[et][j] = (short)((const unsigned short*)att_W2)[k0 * D_SZ + col];
                        w3f[et][j] = (short)((const unsigned short*)att_W2)[(k0 + 32) * D_SZ + col];
                    } else {
                        w0[j]      = (short)f2bfbits(((const float*)att_W1)[k0 * D_SZ + col]);
                        w1[j]      = (short)f2bfbits(((const float*)att_W1)[(k0 + 32) * D_SZ + col]);
                        w2f[et][j] = (short)f2bfbits(((const float*)att_W2)[k0 * D_SZ + col]);
                        w3f[et][j] = (short)f2bfbits(((const float*)att_W2)[(k0 + 32) * D_SZ + col]);
                    }
                }
            }
            f32x4 z = {0.f, 0.f, 0.f, 0.f};
            z = __builtin_amdgcn_mfma_f32_16x16x32_bf16(a0, w0, z, 0, 0, 0);
            z = __builtin_amdgcn_mfma_f32_16x16x32_bf16(a1, w1, z, 0, 0, 0);
            accN[et] = z;
            ve[et]   = LD<FMODE>(att_v, et * 16 + m16);
        }

        #pragma unroll
        for (int mt = 0; mt < 4; ++mt) {
            const unsigned short* Ar = sm.A + (r * 65 + mt * 16 + m16) * ARS + quad * 8;
            const bf16x8 a2 = *(const bf16x8*)Ar;          // neigh k  0..31
            const bf16x8 a3 = *(const bf16x8*)(Ar + 32);   // neigh k 32..63
            float p0 = 0.f, p1 = 0.f, p2 = 0.f, p3 = 0.f;
            #pragma unroll
            for (int et = 0; et < 4; ++et) {
                f32x4 acc = __builtin_amdgcn_mfma_f32_16x16x32_bf16(a2, w2f[et], accN[et], 0, 0, 0);
                acc       = __builtin_amdgcn_mfma_f32_16x16x32_bf16(a3, w3f[et], acc,      0, 0, 0);
                p0 = fmaf(tanh_fast(acc[0]), ve[et], p0);
                p1 = fmaf(tanh_fast(acc[1]), ve[et], p1);
                p2 = fmaf(tanh_fast(acc[2]), ve[et], p2);
                p3 = fmaf(tanh_fast(acc[3]), ve[et], p3);
            }
            p0 = dpp_add<0xB1>(p0); p0 = dpp_add<0x4E>(p0); p0 = dpp_add<0x124>(p0); p0 = dpp_add<0x128>(p0);
            p1 = dpp_add<0xB1>(p1); p1 = dpp_add<0x4E>(p1); p1 = dpp_add<0x124>(p1); p1 = dpp_add<0x128>(p1);
            p2 = dpp_add<0xB1>(p2); p2 = dpp_add<0x4E>(p2); p2 = dpp_add<0x124>(p2); p2 = dpp_add<0x128>(p2);
            p3 = dpp_add<0xB1>(p3); p3 = dpp_add<0x4E>(p3); p3 = dpp_add<0x124>(p3); p3 = dpp_add<0x128>(p3);
            if (m16 == 0) {
                sm.att[r][mt * 16 + quad * 4 + 0] = p0;
                sm.att[r][mt * 16 + quad * 4 + 1] = p1;
                sm.att[r][mt * 16 + quad * 4 + 2] = p2;
                sm.att[r][mt * 16 + quad * 4 + 3] = p3;
            }
        }
    } else {
        // wave 3: coefficient c[n] = mask*leakyrelu(decay)/n_in  and hist staging, rows 0..2
        #pragma unroll
        for (int r = 0; r < R_PB; ++r) {
            const int gr  = min(b0 + r, B_SZ - 1);
            const int idx = gr * N_SZ + lane;
            const float dt = LD<FMODE>(dt_neigh, idx);
            const float ts = 1.0f / fmaf(2.0f, dt, 1.0f);   // Decayer(2,'rev')
            const float lr = ts >= 0.0f ? ts : 0.01f * ts;  // leaky_relu
            const float m  = mval(neigh_mask, idx, mmode);
            float cnt = m;
            #pragma unroll
            for (int off = 32; off > 0; off >>= 1) cnt += __shfl_down(cnt, off, 64);
            cnt = __shfl(cnt, 0, 64);
            sm.cf[r][lane] = m * lr / fmaxf(cnt, 1.0f);

            if constexpr (FMODE == 0) {
                const unsigned u = ((const unsigned*)feature_hist)[gr * 64 + lane];
                *(unsigned*)(sm.comb + r * CRS + 2 * D_SZ + 2 * lane) = u;
            } else {
                const float* fh = (const float*)feature_hist + gr * 2 * D_SZ + 2 * lane;
                *(unsigned*)(sm.comb + r * CRS + 2 * D_SZ + 2 * lane) = pack2bf(fh[0], fh[1]);
            }
        }
    }
    __syncthreads();

    // ---- Phase 4: neigh_agg (waves 0-2; lane = d; wn = cf*att folded in) ----
    if (wv < R_PB) {
        const int r = wv;
        float g0 = 0.f, g1 = 0.f, g2 = 0.f, g3 = 0.f;
        #pragma unroll
        for (int n = 0; n < N_SZ; n += 4) {
            g0 = fmaf(sm.cf[r][n + 0] * sm.att[r][n + 0], bits2f(sm.A[(r * 65 + n + 0) * ARS + lane]), g0);
            g1 = fmaf(sm.cf[r][n + 1] * sm.att[r][n + 1], bits2f(sm.A[(r * 65 + n + 1) * ARS + lane]), g1);
            g2 = fmaf(sm.cf[r][n + 2] * sm.att[r][n + 2], bits2f(sm.A[(r * 65 + n + 2) * ARS + lane]), g2);
            g3 = fmaf(sm.cf[r][n + 3] * sm.att[r][n + 3], bits2f(sm.A[(r * 65 + n + 3) * ARS + lane]), g3);
        }
        const float agg = (g0 + g1) + (g2 + g3);
        sm.comb[r * CRS + D_SZ + lane] = (unsigned short)f2bfbits(agg);
    }
    __syncthreads();

    // ---- Phase 5: GEMV via MFMA. A rows = comb[m16&3] (row 3 zeroed), N=128 h, K=256 ----
    {
        #pragma unroll
        for (int t2 = 0; t2 < 2; ++t2) {
            const int nt = wv * 2 + t2;
            f32x4 c = {0.f, 0.f, 0.f, 0.f};
            #pragma unroll
            for (int ks = 0; ks < 8; ++ks) {
                const bf16x8 af = *(const bf16x8*)(sm.comb + (m16 & 3) * CRS + ks * 32 + quad * 8);
                bf16x8 bw;
                if constexpr (FMODE == 0) {
                    bw = *(const bf16x8*)((const unsigned short*)weight
                            + (nt * 16 + m16) * (4 * D_SZ) + ks * 32 + quad * 8);
                } else {
                    const float* wr = (const float*)weight
                            + (nt * 16 + m16) * (4 * D_SZ) + ks * 32 + quad * 8;
                    #pragma unroll
                    for (int j = 0; j < 8; ++j) bw[j] = (short)f2bfbits(wr[j]);
                }
                c = __builtin_amdgcn_mfma_f32_16x16x32_bf16(af, bw, c, 0, 0, 0);
            }
            if (quad == 0) {   // C rows = quad 0, regs 0..3; col = m16; rows 0..2 valid
                #pragma unroll
                for (int rr = 0; rr < R_PB; ++rr) {
                    if (b0 + rr < B_SZ) {
                        const float v = fmaxf(c[rr], 0.0f);
                        if constexpr (FMODE == 0)
                            ((__hip_bfloat16*)out)[(b0 + rr) * H_SZ + nt * 16 + m16] = __float2bfloat16(v);
                        else
                            ((float*)out)[(b0 + rr) * H_SZ + nt * 16 + m16] = v;
                    }
                }
            }
        }
    }
}

template<bool USE_WS>
__global__ __launch_bounds__(256, 4) void fused_model_kernel(
    const void* dt_node, const void* deg_node, const void* cc_node,
    const void* dt_neigh, const void* deg_neigh, const void* cc_neigh,
    const void* neigh_mask, const void* feature_hist,
    const void* t2v_w, const void* t2v_b, const void* node_w, const void* node_b,
    const void* att_W1, const void* att_W2, const void* att_v,
    const void* weight, void* out, const void* ws)
{
    __shared__ Smem sm;
    const int b0  = blockIdx.x * R_PB;
    const int tid = threadIdx.x;

    // wave-uniform dtype detection on head bytes (no LDS, no barrier)
    const int fmode = __builtin_amdgcn_readfirstlane(detect_f32(dt_node));
    const int mmode = __builtin_amdgcn_readfirstlane(detect_mask_mode(neigh_mask));

    if (fmode == 0)
        body<0, USE_WS>(sm, dt_node, deg_node, cc_node, dt_neigh, deg_neigh, cc_neigh,
                        neigh_mask, feature_hist, t2v_w, t2v_b, node_w, node_b,
                        att_W1, att_W2, att_v, weight, out, ws, mmode, b0, tid);
    else
        body<1, USE_WS>(sm, dt_node, deg_node, cc_node, dt_neigh, deg_neigh, cc_neigh,
                        neigh_mask, feature_hist, t2v_w, t2v_b, node_w, node_b,
                        att_W1, att_W2, att_v, weight, out, ws, mmode, b0, tid);
}

extern "C" void kernel_launch(void* const* d_in, const int* in_sizes, int n_in,
                              void* d_out, int out_size, void* d_ws, size_t ws_size,
                              hipStream_t stream) {
    const bool use_ws = (ws_size >= 16384) && (d_ws != nullptr);
    if (use_ws) {
        prep_kernel<<<4, 256, 0, stream>>>(d_in[0], d_in[12], d_in[13], d_ws);
        fused_model_kernel<true><<<GRID, 256, 0, stream>>>(
            d_in[0], d_in[1], d_in[2], d_in[3], d_in[4], d_in[5], d_in[6], d_in[7],
            d_in[8], d_in[9], d_in[10], d_in[11], d_in[12], d_in[13], d_in[14], d_in[15],
            d_out, d_ws);
    } else {
        fused_model_kernel<false><<<GRID, 256, 0, stream>>>(
            d_in[0], d_in[1], d_in[2], d_in[3], d_in[4], d_in[5], d_in[6], d_in[7],
            d_in[8], d_in[9], d_in[10], d_in[11], d_in[12], d_in[13], d_in[14], d_in[15],
            d_out, d_ws);
    }
}

// Round 14
// 213.728 us; speedup vs baseline: 1.1245x; 1.1245x over previous
//
#include <hip/hip_runtime.h>
#include <hip/hip_bf16.h>

#define B_SZ 16384
#define N_SZ 64
#define D_SZ 64
#define H_SZ 128
#define R_PB 4              // rows per block (best amortization at pinned ~3.2 blocks/CU residency)
#define ARS 68              // A row stride, bf16 elems (136 B; 2-way banks = free)
#define CRS 264             // comb row stride, bf16 elems (payload 256 elems)

typedef short bf16x8 __attribute__((ext_vector_type(8)));
typedef float f32x4  __attribute__((ext_vector_type(4)));
typedef float f32x2  __attribute__((ext_vector_type(2)));

#define INV2PI 0.15915494309189535f
#define TWO_PI 6.283185307179586f

__device__ __forceinline__ float bits2f(unsigned short r){union{unsigned i;float f;}c;c.i=((unsigned)r)<<16;return c.f;}
__device__ __forceinline__ unsigned f2bfbits(float f){
    __hip_bfloat16 h = __float2bfloat16(f);           // RNE
    unsigned short u;
    __builtin_memcpy(&u, &h, 2);
    return (unsigned)u;
}
__device__ __forceinline__ unsigned pack2bf(float a, float b){   // v_cvt_pk_bf16_f32
    __hip_bfloat162 h = __float22bfloat162_rn(make_float2(a, b));
    unsigned r;
    __builtin_memcpy(&r, &h, 4);
    return r;
}
__device__ __forceinline__ float bf2f(__hip_bfloat16 x) { return __bfloat162float(x); }

template<int CTRL>
__device__ __forceinline__ float dpp_add(float v){
    int t = __builtin_amdgcn_mov_dpp(__builtin_bit_cast(int, v), CTRL, 0xf, 0xf, true);
    return v + __builtin_bit_cast(float, t);
}

// cos(2*pi*v): params pre-scaled by 1/2pi -> v_fract + v_cos (HW cos takes revolutions)
// [verified on HW round 13: passed with identical absmax]
__device__ __forceinline__ float cos_rev(float v){
#if __has_builtin(__builtin_amdgcn_cosf)
    return __builtin_amdgcn_cosf(v - floorf(v));
#else
    return __cosf(v * TWO_PI);
#endif
}

__device__ __forceinline__ float tanh_fast(float x){
    float e = exp2f(x * 2.8853900817779268f);          // 2*log2(e) folded into one mul
    return 1.0f - __fdividef(2.0f, e + 1.0f);          // exact at +-inf saturation
}

// FMODE 0: bf16 tensors, 1: f32 tensors
template<int FMODE>
__device__ __forceinline__ float LD(const void* p, int i) {
    if constexpr (FMODE == 0) return bf2f(((const __hip_bfloat16*)p)[i]);
    else                      return ((const float*)p)[i];
}

// mask modes: 0 = int32, 1 = int8/bool, 2 = bf16, 3 = f32
__device__ __forceinline__ float mval(const void* p, int i, int mode) {
    if (mode == 0) return ((const int*)p)[i]            ? 1.0f : 0.0f;
    if (mode == 1) return ((const unsigned char*)p)[i]  ? 1.0f : 0.0f;
    if (mode == 2) return ((const unsigned short*)p)[i] ? 1.0f : 0.0f;
    return ((const unsigned int*)p)[i]                  ? 1.0f : 0.0f;
}

// dt_node strictly positive: bf16 words never set bit15; f32 low-mantissa words do (w.p. 1-2^-32)
__device__ __forceinline__ int detect_f32(const void* p) {
    const uint4* q = (const uint4*)p;
    unsigned o = 0;
    #pragma unroll
    for (int i = 0; i < 8; ++i) { uint4 v = q[i]; o |= v.x | v.y | v.z | v.w; }
    return (o & 0x80008000u) ? 1 : 0;
}

// 0/1-valued mask, 128 head bytes (see earlier rounds)
__device__ __forceinline__ int detect_mask_mode(const void* p) {
    const uint4* q = (const uint4*)p;
    unsigned oa = 0, ofe = 0;
    #pragma unroll
    for (int i = 0; i < 8; ++i) {
        uint4 v = q[i];
        unsigned w = v.x | v.y | v.z | v.w;
        oa  |= w;
        ofe |= (v.x & 0xFEFEFEFEu) | (v.y & 0xFEFEFEFEu) | (v.z & 0xFEFEFEFEu) | (v.w & 0xFEFEFEFEu);
    }
    if ((oa & 0xFFFFFF00u) == 0) return 0;   // int32 0/1
    if (ofe == 0)                return 1;   // bool/int8
    if (oa & 0x000000FEu)        return 2;   // bf16
    return 3;                                // f32
}

// ---------------- prep: W1/W2 -> MFMA B-fragment layout in d_ws (16 KB), grid=4 ----------------
__global__ void prep_kernel(const void* dt_node, const void* att_W1, const void* att_W2,
                            void* ws) {
    const int t     = blockIdx.x * 256 + threadIdx.x;
    const int fmode = detect_f32(dt_node);
    const int fi  = t >> 6, ln = t & 63;
    const int et  = fi >> 2, ks = fi & 3;
    const int m16 = ln & 15, qd = ln >> 4;
    const int col = et * 16 + m16;
    unsigned short s[8];
    #pragma unroll
    for (int j = 0; j < 8; ++j) {
        const int i = ks * 32 + qd * 8 + j;
        if (fmode == 0) {
            s[j] = (i < 64) ? ((const unsigned short*)att_W1)[i * D_SZ + col]
                            : ((const unsigned short*)att_W2)[(i - 64) * D_SZ + col];
        } else {
            const float v = (i < 64) ? ((const float*)att_W1)[i * D_SZ + col]
                                     : ((const float*)att_W2)[(i - 64) * D_SZ + col];
            s[j] = (unsigned short)f2bfbits(v);
        }
    }
    ((uint4*)ws)[t] = make_uint4(((unsigned)s[0]) | (((unsigned)s[1]) << 16),
                                 ((unsigned)s[2]) | (((unsigned)s[3]) << 16),
                                 ((unsigned)s[4]) | (((unsigned)s[5]) << 16),
                                 ((unsigned)s[6]) | (((unsigned)s[7]) << 16));
}

struct Smem {
    alignas(16) unsigned short A[R_PB * 65 * ARS];  // [row][n 0..63 | node=64][d] normalized bf16
    alignas(16) unsigned short comb[R_PB * CRS];    // [node_f(64) | agg(64) | hist(128)] bf16 + pad
    alignas(16) float prm[4][D_SZ];                 // t2v_w/2pi | t2v_b/2pi | node_w | 2*node_b
    float att[R_PB][N_SZ];
    float wn[R_PB][N_SZ];
};

// one 16-channel chunk of a feature row; params from LDS (pre-scaled); 2-inst cos;
// norm reduced across the 4 chunk-threads (width-4 shfl). snb PRE-DOUBLED.
__device__ __forceinline__ void feat_row(float t, float dc,
                                         const float* sw, const float* sb,
                                         const float* snw, const float* snb,
                                         int c, unsigned short* dstA, unsigned short* dstC) {
    f32x2 fp[8]; float ss = 0.0f;
    #pragma unroll
    for (int g = 0; g < 8; ++g) {
        const f32x2 w  = *(const f32x2*)(sw  + 2 * g);
        const f32x2 b  = *(const f32x2*)(sb  + 2 * g);
        const f32x2 nw = *(const f32x2*)(snw + 2 * g);
        const f32x2 nb = *(const f32x2*)(snb + 2 * g);
        f32x2 v = w * t + b;                            // v_pk_fma_f32 (arg in revolutions)
        f32x2 cv;
        cv.x = (c == 0 && g == 0) ? v.x * TWO_PI : cos_rev(v.x);   // channel 0 linear
        cv.y = cos_rev(v.y);
        f32x2 f = cv + (nw * dc + nb);                  // pk_fma + pk_add
        ss = fmaf(f.x, f.x, ss);
        ss = fmaf(f.y, f.y, ss);
        fp[g] = f;
    }
    ss += __shfl_xor(ss, 1, 4);
    ss += __shfl_xor(ss, 2, 4);
    const float inv = 1.0f / fmaxf(sqrtf(ss), 1e-12f);
    unsigned pk[8];
    #pragma unroll
    for (int g = 0; g < 8; ++g)
        pk[g] = pack2bf(fp[g].x * inv, fp[g].y * inv);  // v_cvt_pk_bf16_f32
    uint4 v0 = make_uint4(pk[0], pk[1], pk[2], pk[3]);
    uint4 v1 = make_uint4(pk[4], pk[5], pk[6], pk[7]);
    ((uint4*)dstA)[0] = v0; ((uint4*)dstA)[1] = v1;
    if (dstC) { ((uint4*)dstC)[0] = v0; ((uint4*)dstC)[1] = v1; }
}

template<int FMODE, bool USE_WS>
__device__ __forceinline__ void body(
    Smem& sm,
    const void* dt_node, const void* deg_node, const void* cc_node,
    const void* dt_neigh, const void* deg_neigh, const void* cc_neigh,
    const void* neigh_mask, const void* feature_hist,
    const void* t2v_w, const void* t2v_b, const void* node_w, const void* node_b,
    const void* att_W1, const void* att_W2, const void* att_v,
    const void* weight, void* out, const void* ws, int mmode, int b0, int tid)
{
    const int lane = tid & 63;
    const int wv   = tid >> 6;
    const int m16  = lane & 15;
    const int quad = lane >> 4;

    // ---- Phase 0: stage params into LDS (1 load/thread; wave-uniform branch) ----
    {
        const int arr = tid >> 6, ch = tid & 63;
        float v;
        if      (arr == 0) v = LD<FMODE>(t2v_w,  ch) * INV2PI;
        else if (arr == 1) v = LD<FMODE>(t2v_b,  ch) * INV2PI;
        else if (arr == 2) v = LD<FMODE>(node_w, ch);
        else               v = 2.0f * LD<FMODE>(node_b, ch);   // deg-bias + cc-bias folded
        sm.prm[arr][ch] = v;
    }
    __syncthreads();

    // ---- Phase 1: features. 1040 tasks = (4 rows x 65 feat-rows) x 4 chunks ----
    {
        const int c = tid & 3, d0 = c * 16;               // chunk invariant across iterations
        const float* sw  = sm.prm[0] + d0;
        const float* sb  = sm.prm[1] + d0;
        const float* snw = sm.prm[2] + d0;
        const float* snb = sm.prm[3] + d0;

        #pragma unroll
        for (int it = 0; it < 5; ++it) {
            const int t = tid + it * 256;
            if (t < R_PB * 65 * 4) {
                const int f = t >> 2;
                if (f < R_PB * 64) {
                    const int row = f >> 6, n = f & 63;
                    const int idx = (b0 + row) * N_SZ + n;
                    const float tn  = fabsf(LD<FMODE>(dt_neigh, idx));
                    const float dcn = LD<FMODE>(deg_neigh, idx) + LD<FMODE>(cc_neigh, idx);
                    feat_row(tn, dcn, sw, sb, snw, snb, c,
                             sm.A + (row * 65 + n) * ARS + d0, nullptr);
                } else {
                    const int row = f - R_PB * 64;
                    const float tn = fabsf(LD<FMODE>(dt_node, b0 + row));
                    const float dc = LD<FMODE>(deg_node, b0 + row) + LD<FMODE>(cc_node, b0 + row);
                    feat_row(tn, dc, sw, sb, snw, snb, c,
                             sm.A + (row * 65 + 64) * ARS + d0,
                             sm.comb + row * CRS + d0);
                }
            }
        }
    }
    __syncthreads();

    // ---- Phase 2: S + att for row r = wv (wave-private to the end of phase 4) ----
    // S[m][e] = node@W1[e] (identical rows -> once per e-tile) + neigh[m]@W2[e]
    {
        const int r = wv;
        const unsigned short* An = sm.A + (r * 65 + 64) * ARS + quad * 8;
        const bf16x8 a0 = *(const bf16x8*)An;          // node k  0..31
        const bf16x8 a1 = *(const bf16x8*)(An + 32);   // node k 32..63
        const bf16x8* wfrag = (const bf16x8*)ws;

        f32x4  accN[4];
        bf16x8 w2f[4], w3f[4];
        float  ve[4];
        #pragma unroll
        for (int et = 0; et < 4; ++et) {
            bf16x8 w0, w1;
            if constexpr (USE_WS) {
                w0      = wfrag[(et * 4 + 0) * 64 + lane];
                w1      = wfrag[(et * 4 + 1) * 64 + lane];
                w2f[et] = wfrag[(et * 4 + 2) * 64 + lane];
                w3f[et] = wfrag[(et * 4 + 3) * 64 + lane];
            } else {
                const int col = et * 16 + m16;
                #pragma unroll
                for (int j = 0; j < 8; ++j) {
                    const int k0 = quad * 8 + j;
                    if constexpr (FMODE == 0) {
                        w0[j]      = (short)((const unsigned short*)att_W1)[k0 * D_SZ + col];
                        w1[j]      = (short)((const unsigned short*)att_W1)[(k0 + 32) * D_SZ + col];
                        w2f[et][j] = (short)((const unsigned short*)att_W2)[k0 * D_SZ + col];
                        w3f[et][j] = (short)((const unsigned short*)att_W2)[(k0 + 32) * D_SZ + col];
                    } else {
                        w0[j]      = (short)f2bfbits(((const float*)att_W1)[k0 * D_SZ + col]);
                        w1[j]      = (short)f2bfbits(((const float*)att_W1)[(k0 + 32) * D_SZ + col]);
                        w2f[et][j] = (short)f2bfbits(((const float*)att_W2)[k0 * D_SZ + col]);
                        w3f[et][j] = (short)f2bfbits(((const float*)att_W2)[(k0 + 32) * D_SZ + col]);
                    }
                }
            }
            f32x4 z = {0.f, 0.f, 0.f, 0.f};
            z = __builtin_amdgcn_mfma_f32_16x16x32_bf16(a0, w0, z, 0, 0, 0);
            z = __builtin_amdgcn_mfma_f32_16x16x32_bf16(a1, w1, z, 0, 0, 0);
            accN[et] = z;
            ve[et]   = LD<FMODE>(att_v, et * 16 + m16);
        }

        #pragma unroll
        for (int mt = 0; mt < 4; ++mt) {
            const unsigned short* Ar = sm.A + (r * 65 + mt * 16 + m16) * ARS + quad * 8;
            const bf16x8 a2 = *(const bf16x8*)Ar;          // neigh k  0..31
            const bf16x8 a3 = *(const bf16x8*)(Ar + 32);   // neigh k 32..63
            float p0 = 0.f, p1 = 0.f, p2 = 0.f, p3 = 0.f;
            #pragma unroll
            for (int et = 0; et < 4; ++et) {
                f32x4 acc = __builtin_amdgcn_mfma_f32_16x16x32_bf16(a2, w2f[et], accN[et], 0, 0, 0);
                acc       = __builtin_amdgcn_mfma_f32_16x16x32_bf16(a3, w3f[et], acc,      0, 0, 0);
                p0 = fmaf(tanh_fast(acc[0]), ve[et], p0);
                p1 = fmaf(tanh_fast(acc[1]), ve[et], p1);
                p2 = fmaf(tanh_fast(acc[2]), ve[et], p2);
                p3 = fmaf(tanh_fast(acc[3]), ve[et], p3);
            }
            p0 = dpp_add<0xB1>(p0); p0 = dpp_add<0x4E>(p0); p0 = dpp_add<0x124>(p0); p0 = dpp_add<0x128>(p0);
            p1 = dpp_add<0xB1>(p1); p1 = dpp_add<0x4E>(p1); p1 = dpp_add<0x124>(p1); p1 = dpp_add<0x128>(p1);
            p2 = dpp_add<0xB1>(p2); p2 = dpp_add<0x4E>(p2); p2 = dpp_add<0x124>(p2); p2 = dpp_add<0x128>(p2);
            p3 = dpp_add<0xB1>(p3); p3 = dpp_add<0x4E>(p3); p3 = dpp_add<0x124>(p3); p3 = dpp_add<0x128>(p3);
            if (m16 == 0) {
                sm.att[r][mt * 16 + quad * 4 + 0] = p0;
                sm.att[r][mt * 16 + quad * 4 + 1] = p1;
                sm.att[r][mt * 16 + quad * 4 + 2] = p2;
                sm.att[r][mt * 16 + quad * 4 + 3] = p3;
            }
        }
    }

    // ---- Phase 3: scores -> wn; feature_hist -> comb (wave-private, same wave as P2) ----
    {
        const int r   = wv;
        const int idx = (b0 + r) * N_SZ + lane;
        const float dt = LD<FMODE>(dt_neigh, idx);
        const float ts = 1.0f / fmaf(2.0f, dt, 1.0f);   // Decayer(2,'rev')
        const float lr = ts >= 0.0f ? ts : 0.01f * ts;  // leaky_relu
        const float m  = mval(neigh_mask, idx, mmode);
        float cnt = m;
        #pragma unroll
        for (int off = 32; off > 0; off >>= 1) cnt += __shfl_down(cnt, off, 64);
        cnt = __shfl(cnt, 0, 64);
        sm.wn[r][lane] = m * lr * sm.att[r][lane] / fmaxf(cnt, 1.0f);

        if constexpr (FMODE == 0) {
            const unsigned u = ((const unsigned*)feature_hist)[(b0 + r) * 64 + lane];
            *(unsigned*)(sm.comb + r * CRS + 2 * D_SZ + 2 * lane) = u;
        } else {
            const float* fh = (const float*)feature_hist + (b0 + r) * 2 * D_SZ + 2 * lane;
            *(unsigned*)(sm.comb + r * CRS + 2 * D_SZ + 2 * lane) = pack2bf(fh[0], fh[1]);
        }
    }

    // ---- Phase 4: neigh_agg (wave-private; lane = d; 4 partial accs break the fma chain) ----
    {
        const int r = wv;
        float g0 = 0.f, g1 = 0.f, g2 = 0.f, g3 = 0.f;
        #pragma unroll
        for (int n = 0; n < N_SZ; n += 4) {
            g0 = fmaf(sm.wn[r][n + 0], bits2f(sm.A[(r * 65 + n + 0) * ARS + lane]), g0);
            g1 = fmaf(sm.wn[r][n + 1], bits2f(sm.A[(r * 65 + n + 1) * ARS + lane]), g1);
            g2 = fmaf(sm.wn[r][n + 2], bits2f(sm.A[(r * 65 + n + 2) * ARS + lane]), g2);
            g3 = fmaf(sm.wn[r][n + 3], bits2f(sm.A[(r * 65 + n + 3) * ARS + lane]), g3);
        }
        const float agg = (g0 + g1) + (g2 + g3);
        sm.comb[r * CRS + D_SZ + lane] = (unsigned short)f2bfbits(agg);
    }
    __syncthreads();

    // ---- Phase 5: GEMV via MFMA. A rows = comb[m16&3] (duplicated), N=128 h, K=256 ----
    {
        #pragma unroll
        for (int t2 = 0; t2 < 2; ++t2) {
            const int nt = wv * 2 + t2;
            f32x4 c = {0.f, 0.f, 0.f, 0.f};
            #pragma unroll
            for (int ks = 0; ks < 8; ++ks) {
                const bf16x8 af = *(const bf16x8*)(sm.comb + (m16 & 3) * CRS + ks * 32 + quad * 8);
                bf16x8 bw;
                if constexpr (FMODE == 0) {
                    bw = *(const bf16x8*)((const unsigned short*)weight
                            + (nt * 16 + m16) * (4 * D_SZ) + ks * 32 + quad * 8);
                } else {
                    const float* wr = (const float*)weight
                            + (nt * 16 + m16) * (4 * D_SZ) + ks * 32 + quad * 8;
                    #pragma unroll
                    for (int j = 0; j < 8; ++j) bw[j] = (short)f2bfbits(wr[j]);
                }
                c = __builtin_amdgcn_mfma_f32_16x16x32_bf16(af, bw, c, 0, 0, 0);
            }
            if (quad == 0) {   // C rows 0..3 = quad 0, regs 0..3; col = m16
                #pragma unroll
                for (int rr = 0; rr < R_PB; ++rr) {
                    const float v = fmaxf(c[rr], 0.0f);
                    if constexpr (FMODE == 0)
                        ((__hip_bfloat16*)out)[(b0 + rr) * H_SZ + nt * 16 + m16] = __float2bfloat16(v);
                    else
                        ((float*)out)[(b0 + rr) * H_SZ + nt * 16 + m16] = v;
                }
            }
        }
    }
}

template<bool USE_WS>
__global__ __launch_bounds__(256, 4) void fused_model_kernel(
    const void* dt_node, const void* deg_node, const void* cc_node,
    const void* dt_neigh, const void* deg_neigh, const void* cc_neigh,
    const void* neigh_mask, const void* feature_hist,
    const void* t2v_w, const void* t2v_b, const void* node_w, const void* node_b,
    const void* att_W1, const void* att_W2, const void* att_v,
    const void* weight, void* out, const void* ws)
{
    __shared__ Smem sm;
    const int b0  = blockIdx.x * R_PB;
    const int tid = threadIdx.x;

    // wave-uniform dtype detection on head bytes (no LDS, no barrier)
    const int fmode = __builtin_amdgcn_readfirstlane(detect_f32(dt_node));
    const int mmode = __builtin_amdgcn_readfirstlane(detect_mask_mode(neigh_mask));

    if (fmode == 0)
        body<0, USE_WS>(sm, dt_node, deg_node, cc_node, dt_neigh, deg_neigh, cc_neigh,
                        neigh_mask, feature_hist, t2v_w, t2v_b, node_w, node_b,
                        att_W1, att_W2, att_v, weight, out, ws, mmode, b0, tid);
    else
        body<1, USE_WS>(sm, dt_node, deg_node, cc_node, dt_neigh, deg_neigh, cc_neigh,
                        neigh_mask, feature_hist, t2v_w, t2v_b, node_w, node_b,
                        att_W1, att_W2, att_v, weight, out, ws, mmode, b0, tid);
}

extern "C" void kernel_launch(void* const* d_in, const int* in_sizes, int n_in,
                              void* d_out, int out_size, void* d_ws, size_t ws_size,
                              hipStream_t stream) {
    const bool use_ws = (ws_size >= 16384) && (d_ws != nullptr);
    if (use_ws) {
        prep_kernel<<<4, 256, 0, stream>>>(d_in[0], d_in[12], d_in[13], d_ws);
        fused_model_kernel<true><<<B_SZ / R_PB, 256, 0, stream>>>(
            d_in[0], d_in[1], d_in[2], d_in[3], d_in[4], d_in[5], d_in[6], d_in[7],
            d_in[8], d_in[9], d_in[10], d_in[11], d_in[12], d_in[13], d_in[14], d_in[15],
            d_out, d_ws);
    } else {
        fused_model_kernel<false><<<B_SZ / R_PB, 256, 0, stream>>>(
            d_in[0], d_in[1], d_in[2], d_in[3], d_in[4], d_in[5], d_in[6], d_in[7],
            d_in[8], d_in[9], d_in[10], d_in[11], d_in[12], d_in[13], d_in[14], d_in[15],
            d_out, d_ws);
    }
}

// Round 15
// 210.434 us; speedup vs baseline: 1.1421x; 1.0157x over previous
//
#include <hip/hip_runtime.h>
#include <hip/hip_bf16.h>

#define B_SZ 16384
#define N_SZ 64
#define D_SZ 64
#define H_SZ 128
#define R_PB 4              // rows per block
#define ARS 68              // A row stride, bf16 elems (136 B; 2-way banks = free)
#define CRS 264             // comb row stride, bf16 elems (payload 256 elems)

typedef short bf16x8 __attribute__((ext_vector_type(8)));
typedef float f32x4  __attribute__((ext_vector_type(4)));
typedef float f32x2  __attribute__((ext_vector_type(2)));

__device__ __forceinline__ float bits2f(unsigned short r){union{unsigned i;float f;}c;c.i=((unsigned)r)<<16;return c.f;}
__device__ __forceinline__ unsigned f2bfbits(float f){
    __hip_bfloat16 h = __float2bfloat16(f);           // RNE
    unsigned short u;
    __builtin_memcpy(&u, &h, 2);
    return (unsigned)u;
}
__device__ __forceinline__ unsigned pack2bf(float a, float b){   // v_cvt_pk_bf16_f32
    __hip_bfloat162 h = __float22bfloat162_rn(make_float2(a, b));
    unsigned r;
    __builtin_memcpy(&r, &h, 4);
    return r;
}
__device__ __forceinline__ float bf2f(__hip_bfloat16 x) { return __bfloat162float(x); }

template<int CTRL>
__device__ __forceinline__ float dpp_add(float v){
    int t = __builtin_amdgcn_mov_dpp(__builtin_bit_cast(int, v), CTRL, 0xf, 0xf, true);
    return v + __builtin_bit_cast(float, t);
}

__device__ __forceinline__ float tanh_fast(float x){
    float e = __expf(2.0f * x);
    return 1.0f - __fdividef(2.0f, e + 1.0f);         // exact at +-inf saturation
}

// FMODE 0: bf16 tensors, 1: f32 tensors
template<int FMODE>
__device__ __forceinline__ float LD(const void* p, int i) {
    if constexpr (FMODE == 0) return bf2f(((const __hip_bfloat16*)p)[i]);
    else                      return ((const float*)p)[i];
}

// mask modes: 0 = int32, 1 = int8/bool, 2 = bf16, 3 = f32
__device__ __forceinline__ float mval(const void* p, int i, int mode) {
    if (mode == 0) return ((const int*)p)[i]            ? 1.0f : 0.0f;
    if (mode == 1) return ((const unsigned char*)p)[i]  ? 1.0f : 0.0f;
    if (mode == 2) return ((const unsigned short*)p)[i] ? 1.0f : 0.0f;
    return ((const unsigned int*)p)[i]                  ? 1.0f : 0.0f;
}

// dt_node strictly positive: bf16 words never set bit15; f32 low-mantissa words do (w.p. 1-2^-32)
__device__ __forceinline__ int detect_f32(const void* p) {
    const uint4* q = (const uint4*)p;
    unsigned o = 0;
    #pragma unroll
    for (int i = 0; i < 8; ++i) { uint4 v = q[i]; o |= v.x | v.y | v.z | v.w; }
    return (o & 0x80008000u) ? 1 : 0;
}

// 0/1-valued mask, 128 head bytes: int32 -> only byte0 of each dword nonzero;
// bool -> all bytes <=1; bf16(1.0=0x3F80) -> lo byte 0x80; f32(1.0f) -> lo byte 0
__device__ __forceinline__ int detect_mask_mode(const void* p) {
    const uint4* q = (const uint4*)p;
    unsigned oa = 0, ofe = 0;
    #pragma unroll
    for (int i = 0; i < 8; ++i) {
        uint4 v = q[i];
        unsigned w = v.x | v.y | v.z | v.w;
        oa  |= w;
        ofe |= (v.x & 0xFEFEFEFEu) | (v.y & 0xFEFEFEFEu) | (v.z & 0xFEFEFEFEu) | (v.w & 0xFEFEFEFEu);
    }
    if ((oa & 0xFFFFFF00u) == 0) return 0;   // int32 0/1
    if (ofe == 0)                return 1;   // bool/int8
    if (oa & 0x000000FEu)        return 2;   // bf16
    return 3;                                // f32
}

// ---------------- prep: W1/W2 -> MFMA B-fragment layout in d_ws (16 KB), grid=4 ----------------
// entry t in [0,1024): fi=t>>6 (et=fi>>2, ks=fi&3), lane=t&63 (m16=lane&15, qd=lane>>4)
// holds 8 bf16: Wcat[ks*32+qd*8+j][et*16+m16], Wcat=[W1;W2]
__global__ void prep_kernel(const void* dt_node, const void* att_W1, const void* att_W2,
                            void* ws) {
    const int t     = blockIdx.x * 256 + threadIdx.x;
    const int fmode = detect_f32(dt_node);
    const int fi  = t >> 6, ln = t & 63;
    const int et  = fi >> 2, ks = fi & 3;
    const int m16 = ln & 15, qd = ln >> 4;
    const int col = et * 16 + m16;
    unsigned short s[8];
    #pragma unroll
    for (int j = 0; j < 8; ++j) {
        const int i = ks * 32 + qd * 8 + j;
        if (fmode == 0) {
            s[j] = (i < 64) ? ((const unsigned short*)att_W1)[i * D_SZ + col]
                            : ((const unsigned short*)att_W2)[(i - 64) * D_SZ + col];
        } else {
            const float v = (i < 64) ? ((const float*)att_W1)[i * D_SZ + col]
                                     : ((const float*)att_W2)[(i - 64) * D_SZ + col];
            s[j] = (unsigned short)f2bfbits(v);
        }
    }
    ((uint4*)ws)[t] = make_uint4(((unsigned)s[0]) | (((unsigned)s[1]) << 16),
                                 ((unsigned)s[2]) | (((unsigned)s[3]) << 16),
                                 ((unsigned)s[4]) | (((unsigned)s[5]) << 16),
                                 ((unsigned)s[6]) | (((unsigned)s[7]) << 16));
}

struct Smem {
    alignas(16) unsigned short A[R_PB * 65 * ARS];  // [row][n 0..63 | node=64][d] normalized bf16
    alignas(16) unsigned short comb[R_PB * CRS];    // [node_f(64) | agg(64) | hist(128)] bf16 + pad
    alignas(16) float prm[4][D_SZ];                 // t2v_w | t2v_b | node_w | 2*node_b
    float att[R_PB][N_SZ];
    float wn[R_PB][N_SZ];
};

// one 16-channel chunk of a feature row; params from LDS; packed f32 math (v_pk_fma_f32);
// norm reduced across the 4 chunk-threads (width-4 shfl). snb is PRE-DOUBLED.
__device__ __forceinline__ void feat_row(float t, float dc,
                                         const float* sw, const float* sb,
                                         const float* snw, const float* snb,
                                         int c, unsigned short* dstA, unsigned short* dstC) {
    f32x2 fp[8]; float ss = 0.0f;
    #pragma unroll
    for (int g = 0; g < 8; ++g) {
        const f32x2 w  = *(const f32x2*)(sw  + 2 * g);
        const f32x2 b  = *(const f32x2*)(sb  + 2 * g);
        const f32x2 nw = *(const f32x2*)(snw + 2 * g);
        const f32x2 nb = *(const f32x2*)(snb + 2 * g);
        f32x2 v = w * t + b;                            // v_pk_fma_f32
        f32x2 cv;
        cv.x = (c == 0 && g == 0) ? v.x : __cosf(v.x);  // channel 0 linear, rest cos
        cv.y = __cosf(v.y);
        f32x2 f = cv + (nw * dc + nb);                  // pk_fma + pk_add
        ss = fmaf(f.x, f.x, ss);
        ss = fmaf(f.y, f.y, ss);
        fp[g] = f;
    }
    ss += __shfl_xor(ss, 1, 4);
    ss += __shfl_xor(ss, 2, 4);
    const float inv = 1.0f / fmaxf(sqrtf(ss), 1e-12f);
    unsigned pk[8];
    #pragma unroll
    for (int g = 0; g < 8; ++g)
        pk[g] = pack2bf(fp[g].x * inv, fp[g].y * inv);  // v_cvt_pk_bf16_f32
    uint4 v0 = make_uint4(pk[0], pk[1], pk[2], pk[3]);
    uint4 v1 = make_uint4(pk[4], pk[5], pk[6], pk[7]);
    ((uint4*)dstA)[0] = v0; ((uint4*)dstA)[1] = v1;
    if (dstC) { ((uint4*)dstC)[0] = v0; ((uint4*)dstC)[1] = v1; }
}

template<int FMODE, bool USE_WS>
__device__ __forceinline__ void body(
    Smem& sm,
    const void* dt_node, const void* deg_node, const void* cc_node,
    const void* dt_neigh, const void* deg_neigh, const void* cc_neigh,
    const void* neigh_mask, const void* feature_hist,
    const void* t2v_w, const void* t2v_b, const void* node_w, const void* node_b,
    const void* att_W1, const void* att_W2, const void* att_v,
    const void* weight, void* out, const void* ws, int mmode, int b0, int tid)
{
    const int lane = tid & 63;
    const int wv   = tid >> 6;
    const int m16  = lane & 15;
    const int quad = lane >> 4;

    // ---- Phase 0: stage params into LDS (1 load/thread; wave-uniform branch) ----
    {
        const int arr = tid >> 6, ch = tid & 63;
        float v;
        if      (arr == 0) v = LD<FMODE>(t2v_w,  ch);
        else if (arr == 1) v = LD<FMODE>(t2v_b,  ch);
        else if (arr == 2) v = LD<FMODE>(node_w, ch);
        else               v = 2.0f * LD<FMODE>(node_b, ch);   // deg-bias + cc-bias folded
        sm.prm[arr][ch] = v;
    }
    __syncthreads();

    // ---- Phase 1: features. 1040 tasks = (4 rows x 65 feat-rows) x 4 chunks ----
    {
        const int c = tid & 3, d0 = c * 16;               // chunk invariant across iterations
        const float* sw  = sm.prm[0] + d0;
        const float* sb  = sm.prm[1] + d0;
        const float* snw = sm.prm[2] + d0;
        const float* snb = sm.prm[3] + d0;

        #pragma unroll
        for (int it = 0; it < 5; ++it) {
            const int t = tid + it * 256;
            if (t < R_PB * 65 * 4) {
                const int f = t >> 2;
                if (f < R_PB * 64) {
                    const int row = f >> 6, n = f & 63;
                    const int idx = (b0 + row) * N_SZ + n;
                    const float tn  = fabsf(LD<FMODE>(dt_neigh, idx));
                    const float dcn = LD<FMODE>(deg_neigh, idx) + LD<FMODE>(cc_neigh, idx);
                    feat_row(tn, dcn, sw, sb, snw, snb, c,
                             sm.A + (row * 65 + n) * ARS + d0, nullptr);
                } else {
                    const int row = f - R_PB * 64;
                    const float tn = fabsf(LD<FMODE>(dt_node, b0 + row));
                    const float dc = LD<FMODE>(deg_node, b0 + row) + LD<FMODE>(cc_node, b0 + row);
                    feat_row(tn, dc, sw, sb, snw, snb, c,
                             sm.A + (row * 65 + 64) * ARS + d0,
                             sm.comb + row * CRS + d0);
                }
            }
        }
    }
    __syncthreads();

    // ---- Phase 2: S + att for row r = wv (wave-private to the end of phase 4) ----
    // S[m][e] = node@W1[e] (identical rows -> once per e-tile) + neigh[m]@W2[e]
    {
        const int r = wv;
        const unsigned short* An = sm.A + (r * 65 + 64) * ARS + quad * 8;
        const bf16x8 a0 = *(const bf16x8*)An;          // node k  0..31
        const bf16x8 a1 = *(const bf16x8*)(An + 32);   // node k 32..63
        const bf16x8* wfrag = (const bf16x8*)ws;

        f32x4  accN[4];
        bf16x8 w2f[4], w3f[4];
        float  ve[4];
        #pragma unroll
        for (int et = 0; et < 4; ++et) {
            bf16x8 w0, w1;
            if constexpr (USE_WS) {
                w0      = wfrag[(et * 4 + 0) * 64 + lane];
                w1      = wfrag[(et * 4 + 1) * 64 + lane];
                w2f[et] = wfrag[(et * 4 + 2) * 64 + lane];
                w3f[et] = wfrag[(et * 4 + 3) * 64 + lane];
            } else {
                const int col = et * 16 + m16;
                #pragma unroll
                for (int j = 0; j < 8; ++j) {
                    const int k0 = quad * 8 + j;
                    if constexpr (FMODE == 0) {
                        w0[j]      = (short)((const unsigned short*)att_W1)[k0 * D_SZ + col];
                        w1[j]      = (short)((const unsigned short*)att_W1)[(k0 + 32) * D_SZ + col];
                        w2f[et][j] = (short)((const unsigned short*)att_W2)[k0 * D_SZ + col];
                        w3f[et][j] = (short)((const unsigned short*)att_W2)[(k0 + 32) * D_SZ + col];
                    } else {
                        w0[j]      = (short)f2bfbits(((const float*)att_W1)[k0 * D_SZ + col]);
                        w1[j]      = (short)f2bfbits(((const float*)att_W1)[(k0 + 32) * D_SZ + col]);
                        w2f[et][j] = (short)f2bfbits(((const float*)att_W2)[k0 * D_SZ + col]);
                        w3f[et][j] = (short)f2bfbits(((const float*)att_W2)[(k0 + 32) * D_SZ + col]);
                    }
                }
            }
            f32x4 z = {0.f, 0.f, 0.f, 0.f};
            z = __builtin_amdgcn_mfma_f32_16x16x32_bf16(a0, w0, z, 0, 0, 0);
            z = __builtin_amdgcn_mfma_f32_16x16x32_bf16(a1, w1, z, 0, 0, 0);
            accN[et] = z;
            ve[et]   = LD<FMODE>(att_v, et * 16 + m16);
        }

        #pragma unroll
        for (int mt = 0; mt < 4; ++mt) {
            const unsigned short* Ar = sm.A + (r * 65 + mt * 16 + m16) * ARS + quad * 8;
            const bf16x8 a2 = *(const bf16x8*)Ar;          // neigh k  0..31
            const bf16x8 a3 = *(const bf16x8*)(Ar + 32);   // neigh k 32..63
            float p0 = 0.f, p1 = 0.f, p2 = 0.f, p3 = 0.f;
            #pragma unroll
            for (int et = 0; et < 4; ++et) {
                f32x4 acc = __builtin_amdgcn_mfma_f32_16x16x32_bf16(a2, w2f[et], accN[et], 0, 0, 0);
                acc       = __builtin_amdgcn_mfma_f32_16x16x32_bf16(a3, w3f[et], acc,      0, 0, 0);
                p0 = fmaf(tanh_fast(acc[0]), ve[et], p0);
                p1 = fmaf(tanh_fast(acc[1]), ve[et], p1);
                p2 = fmaf(tanh_fast(acc[2]), ve[et], p2);
                p3 = fmaf(tanh_fast(acc[3]), ve[et], p3);
            }
            p0 = dpp_add<0xB1>(p0); p0 = dpp_add<0x4E>(p0); p0 = dpp_add<0x124>(p0); p0 = dpp_add<0x128>(p0);
            p1 = dpp_add<0xB1>(p1); p1 = dpp_add<0x4E>(p1); p1 = dpp_add<0x124>(p1); p1 = dpp_add<0x128>(p1);
            p2 = dpp_add<0xB1>(p2); p2 = dpp_add<0x4E>(p2); p2 = dpp_add<0x124>(p2); p2 = dpp_add<0x128>(p2);
            p3 = dpp_add<0xB1>(p3); p3 = dpp_add<0x4E>(p3); p3 = dpp_add<0x124>(p3); p3 = dpp_add<0x128>(p3);
            if (m16 == 0) {
                sm.att[r][mt * 16 + quad * 4 + 0] = p0;
                sm.att[r][mt * 16 + quad * 4 + 1] = p1;
                sm.att[r][mt * 16 + quad * 4 + 2] = p2;
                sm.att[r][mt * 16 + quad * 4 + 3] = p3;
            }
        }
    }

    // ---- Phase 3: scores -> wn; feature_hist -> comb (wave-private, same wave as P2) ----
    {
        const int r   = wv;
        const int idx = (b0 + r) * N_SZ + lane;
        const float dt = LD<FMODE>(dt_neigh, idx);
        const float ts = 1.0f / fmaf(2.0f, dt, 1.0f);   // Decayer(2,'rev')
        const float lr = ts >= 0.0f ? ts : 0.01f * ts;  // leaky_relu
        const float m  = mval(neigh_mask, idx, mmode);
        float cnt = m;
        #pragma unroll
        for (int off = 32; off > 0; off >>= 1) cnt += __shfl_down(cnt, off, 64);
        cnt = __shfl(cnt, 0, 64);
        sm.wn[r][lane] = m * lr * sm.att[r][lane] / fmaxf(cnt, 1.0f);

        if constexpr (FMODE == 0) {
            const unsigned u = ((const unsigned*)feature_hist)[(b0 + r) * 64 + lane];
            *(unsigned*)(sm.comb + r * CRS + 2 * D_SZ + 2 * lane) = u;
        } else {
            const float* fh = (const float*)feature_hist + (b0 + r) * 2 * D_SZ + 2 * lane;
            *(unsigned*)(sm.comb + r * CRS + 2 * D_SZ + 2 * lane) = pack2bf(fh[0], fh[1]);
        }
    }

    // ---- Phase 4: neigh_agg (wave-private; lane = d; 4 partial accs break the fma chain) ----
    {
        const int r = wv;
        float g0 = 0.f, g1 = 0.f, g2 = 0.f, g3 = 0.f;
        #pragma unroll
        for (int n = 0; n < N_SZ; n += 4) {
            g0 = fmaf(sm.wn[r][n + 0], bits2f(sm.A[(r * 65 + n + 0) * ARS + lane]), g0);
            g1 = fmaf(sm.wn[r][n + 1], bits2f(sm.A[(r * 65 + n + 1) * ARS + lane]), g1);
            g2 = fmaf(sm.wn[r][n + 2], bits2f(sm.A[(r * 65 + n + 2) * ARS + lane]), g2);
            g3 = fmaf(sm.wn[r][n + 3], bits2f(sm.A[(r * 65 + n + 3) * ARS + lane]), g3);
        }
        const float agg = (g0 + g1) + (g2 + g3);
        sm.comb[r * CRS + D_SZ + lane] = (unsigned short)f2bfbits(agg);
    }
    __syncthreads();

    // ---- Phase 5: GEMV via MFMA. A rows = comb[m16&3] (duplicated), N=128 h, K=256 ----
    // AF hoisted out of the t2 loop: identical for both h-tiles (was read twice in r12)
    {
        bf16x8 AF[8];
        #pragma unroll
        for (int ks = 0; ks < 8; ++ks)
            AF[ks] = *(const bf16x8*)(sm.comb + (m16 & 3) * CRS + ks * 32 + quad * 8);
        #pragma unroll
        for (int t2 = 0; t2 < 2; ++t2) {
            const int nt = wv * 2 + t2;
            f32x4 c = {0.f, 0.f, 0.f, 0.f};
            #pragma unroll
            for (int ks = 0; ks < 8; ++ks) {
                bf16x8 bw;
                if constexpr (FMODE == 0) {
                    bw = *(const bf16x8*)((const unsigned short*)weight
                            + (nt * 16 + m16) * (4 * D_SZ) + ks * 32 + quad * 8);
                } else {
                    const float* wr = (const float*)weight
                            + (nt * 16 + m16) * (4 * D_SZ) + ks * 32 + quad * 8;
                    #pragma unroll
                    for (int j = 0; j < 8; ++j) bw[j] = (short)f2bfbits(wr[j]);
                }
                c = __builtin_amdgcn_mfma_f32_16x16x32_bf16(AF[ks], bw, c, 0, 0, 0);
            }
            if (quad == 0) {   // C rows 0..3 = quad 0, regs 0..3; col = m16
                #pragma unroll
                for (int rr = 0; rr < R_PB; ++rr) {
                    const float v = fmaxf(c[rr], 0.0f);
                    if constexpr (FMODE == 0)
                        ((__hip_bfloat16*)out)[(b0 + rr) * H_SZ + nt * 16 + m16] = __float2bfloat16(v);
                    else
                        ((float*)out)[(b0 + rr) * H_SZ + nt * 16 + m16] = v;
                }
            }
        }
    }
}

template<bool USE_WS>
__global__ __launch_bounds__(256, 4) void fused_model_kernel(
    const void* dt_node, const void* deg_node, const void* cc_node,
    const void* dt_neigh, const void* deg_neigh, const void* cc_neigh,
    const void* neigh_mask, const void* feature_hist,
    const void* t2v_w, const void* t2v_b, const void* node_w, const void* node_b,
    const void* att_W1, const void* att_W2, const void* att_v,
    const void* weight, void* out, const void* ws)
{
    __shared__ Smem sm;
    const int b0  = blockIdx.x * R_PB;
    const int tid = threadIdx.x;

    // wave-uniform dtype detection on head bytes (no LDS, no barrier)
    const int fmode = __builtin_amdgcn_readfirstlane(detect_f32(dt_node));
    const int mmode = __builtin_amdgcn_readfirstlane(detect_mask_mode(neigh_mask));

    if (fmode == 0)
        body<0, USE_WS>(sm, dt_node, deg_node, cc_node, dt_neigh, deg_neigh, cc_neigh,
                        neigh_mask, feature_hist, t2v_w, t2v_b, node_w, node_b,
                        att_W1, att_W2, att_v, weight, out, ws, mmode, b0, tid);
    else
        body<1, USE_WS>(sm, dt_node, deg_node, cc_node, dt_neigh, deg_neigh, cc_neigh,
                        neigh_mask, feature_hist, t2v_w, t2v_b, node_w, node_b,
                        att_W1, att_W2, att_v, weight, out, ws, mmode, b0, tid);
}

extern "C" void kernel_launch(void* const* d_in, const int* in_sizes, int n_in,
                              void* d_out, int out_size, void* d_ws, size_t ws_size,
                              hipStream_t stream) {
    const bool use_ws = (ws_size >= 16384) && (d_ws != nullptr);
    if (use_ws) {
        prep_kernel<<<4, 256, 0, stream>>>(d_in[0], d_in[12], d_in[13], d_ws);
        fused_model_kernel<true><<<B_SZ / R_PB, 256, 0, stream>>>(
            d_in[0], d_in[1], d_in[2], d_in[3], d_in[4], d_in[5], d_in[6], d_in[7],
            d_in[8], d_in[9], d_in[10], d_in[11], d_in[12], d_in[13], d_in[14], d_in[15],
            d_out, d_ws);
    } else {
        fused_model_kernel<false><<<B_SZ / R_PB, 256, 0, stream>>>(
            d_in[0], d_in[1], d_in[2], d_in[3], d_in[4], d_in[5], d_in[6], d_in[7],
            d_in[8], d_in[9], d_in[10], d_in[11], d_in[12], d_in[13], d_in[14], d_in[15],
            d_out, d_ws);
    }
}

// Round 16
// 207.213 us; speedup vs baseline: 1.1599x; 1.0155x over previous
//
#include <hip/hip_runtime.h>
#include <hip/hip_bf16.h>

#define B_SZ 16384
#define N_SZ 64
#define D_SZ 64
#define H_SZ 128
#define R_PB 4              // rows per block
#define ARS 68              // A row stride, bf16 elems (136 B; 2-way banks = free)
#define CRS 264             // comb row stride, bf16 elems (payload 256 elems)

typedef short bf16x8 __attribute__((ext_vector_type(8)));
typedef float f32x4  __attribute__((ext_vector_type(4)));
typedef float f32x2  __attribute__((ext_vector_type(2)));

__device__ __forceinline__ float bits2f(unsigned short r){union{unsigned i;float f;}c;c.i=((unsigned)r)<<16;return c.f;}
__device__ __forceinline__ unsigned f2bfbits(float f){
    __hip_bfloat16 h = __float2bfloat16(f);           // RNE
    unsigned short u;
    __builtin_memcpy(&u, &h, 2);
    return (unsigned)u;
}
__device__ __forceinline__ unsigned pack2bf(float a, float b){   // v_cvt_pk_bf16_f32
    __hip_bfloat162 h = __float22bfloat162_rn(make_float2(a, b));
    unsigned r;
    __builtin_memcpy(&r, &h, 4);
    return r;
}
__device__ __forceinline__ float bf2f(__hip_bfloat16 x) { return __bfloat162float(x); }

template<int CTRL>
__device__ __forceinline__ float dpp_add(float v){
    int t = __builtin_amdgcn_mov_dpp(__builtin_bit_cast(int, v), CTRL, 0xf, 0xf, true);
    return v + __builtin_bit_cast(float, t);
}

// Clamped Pade 3/2: tanh(x) ~ x(27+x^2)/(27+9x^2), clamp [-1,1].
// 1 trans op (v_rcp) vs exp-form's 2 (v_exp + v_rcp); overshoot <=0.023 decorrelates
// across 64 signed v_e terms and is divided by n_in (~45) -> out error ~1e-4.
__device__ __forceinline__ float tanh_fast(float x){
    const float t   = x * x;
    const float num = x * (27.0f + t);
    const float den = fmaf(t, 9.0f, 27.0f);
    const float r   = __fdividef(num, den);            // v_rcp + v_mul
    return fminf(1.0f, fmaxf(-1.0f, r));               // v_med3
}

// FMODE 0: bf16 tensors, 1: f32 tensors
template<int FMODE>
__device__ __forceinline__ float LD(const void* p, int i) {
    if constexpr (FMODE == 0) return bf2f(((const __hip_bfloat16*)p)[i]);
    else                      return ((const float*)p)[i];
}

// mask modes: 0 = int32, 1 = int8/bool, 2 = bf16, 3 = f32
__device__ __forceinline__ float mval(const void* p, int i, int mode) {
    if (mode == 0) return ((const int*)p)[i]            ? 1.0f : 0.0f;
    if (mode == 1) return ((const unsigned char*)p)[i]  ? 1.0f : 0.0f;
    if (mode == 2) return ((const unsigned short*)p)[i] ? 1.0f : 0.0f;
    return ((const unsigned int*)p)[i]                  ? 1.0f : 0.0f;
}

// dt_node strictly positive: bf16 words never set bit15; f32 low-mantissa words do (w.p. 1-2^-32)
__device__ __forceinline__ int detect_f32(const void* p) {
    const uint4* q = (const uint4*)p;
    unsigned o = 0;
    #pragma unroll
    for (int i = 0; i < 8; ++i) { uint4 v = q[i]; o |= v.x | v.y | v.z | v.w; }
    return (o & 0x80008000u) ? 1 : 0;
}

// 0/1-valued mask, 128 head bytes: int32 -> only byte0 of each dword nonzero;
// bool -> all bytes <=1; bf16(1.0=0x3F80) -> lo byte 0x80; f32(1.0f) -> lo byte 0
__device__ __forceinline__ int detect_mask_mode(const void* p) {
    const uint4* q = (const uint4*)p;
    unsigned oa = 0, ofe = 0;
    #pragma unroll
    for (int i = 0; i < 8; ++i) {
        uint4 v = q[i];
        unsigned w = v.x | v.y | v.z | v.w;
        oa  |= w;
        ofe |= (v.x & 0xFEFEFEFEu) | (v.y & 0xFEFEFEFEu) | (v.z & 0xFEFEFEFEu) | (v.w & 0xFEFEFEFEu);
    }
    if ((oa & 0xFFFFFF00u) == 0) return 0;   // int32 0/1
    if (ofe == 0)                return 1;   // bool/int8
    if (oa & 0x000000FEu)        return 2;   // bf16
    return 3;                                // f32
}

// ---------------- prep: W1/W2 -> MFMA B-fragment layout in d_ws (16 KB), grid=4 ----------------
// entry t in [0,1024): fi=t>>6 (et=fi>>2, ks=fi&3), lane=t&63 (m16=lane&15, qd=lane>>4)
// holds 8 bf16: Wcat[ks*32+qd*8+j][et*16+m16], Wcat=[W1;W2]
__global__ void prep_kernel(const void* dt_node, const void* att_W1, const void* att_W2,
                            void* ws) {
    const int t     = blockIdx.x * 256 + threadIdx.x;
    const int fmode = detect_f32(dt_node);
    const int fi  = t >> 6, ln = t & 63;
    const int et  = fi >> 2, ks = fi & 3;
    const int m16 = ln & 15, qd = ln >> 4;
    const int col = et * 16 + m16;
    unsigned short s[8];
    #pragma unroll
    for (int j = 0; j < 8; ++j) {
        const int i = ks * 32 + qd * 8 + j;
        if (fmode == 0) {
            s[j] = (i < 64) ? ((const unsigned short*)att_W1)[i * D_SZ + col]
                            : ((const unsigned short*)att_W2)[(i - 64) * D_SZ + col];
        } else {
            const float v = (i < 64) ? ((const float*)att_W1)[i * D_SZ + col]
                                     : ((const float*)att_W2)[(i - 64) * D_SZ + col];
            s[j] = (unsigned short)f2bfbits(v);
        }
    }
    ((uint4*)ws)[t] = make_uint4(((unsigned)s[0]) | (((unsigned)s[1]) << 16),
                                 ((unsigned)s[2]) | (((unsigned)s[3]) << 16),
                                 ((unsigned)s[4]) | (((unsigned)s[5]) << 16),
                                 ((unsigned)s[6]) | (((unsigned)s[7]) << 16));
}

struct Smem {
    alignas(16) unsigned short A[R_PB * 65 * ARS];  // [row][n 0..63 | node=64][d] normalized bf16
    alignas(16) unsigned short comb[R_PB * CRS];    // [node_f(64) | agg(64) | hist(128)] bf16 + pad
    alignas(16) float prm[4][D_SZ];                 // t2v_w | t2v_b | node_w | 2*node_b
    float att[R_PB][N_SZ];
    float wn[R_PB][N_SZ];
};

// one 16-channel chunk of a feature row; params from LDS; packed f32 math (v_pk_fma_f32);
// norm reduced across the 4 chunk-threads (width-4 shfl). snb is PRE-DOUBLED.
__device__ __forceinline__ void feat_row(float t, float dc,
                                         const float* sw, const float* sb,
                                         const float* snw, const float* snb,
                                         int c, unsigned short* dstA, unsigned short* dstC) {
    f32x2 fp[8]; float ss = 0.0f;
    #pragma unroll
    for (int g = 0; g < 8; ++g) {
        const f32x2 w  = *(const f32x2*)(sw  + 2 * g);
        const f32x2 b  = *(const f32x2*)(sb  + 2 * g);
        const f32x2 nw = *(const f32x2*)(snw + 2 * g);
        const f32x2 nb = *(const f32x2*)(snb + 2 * g);
        f32x2 v = w * t + b;                            // v_pk_fma_f32
        f32x2 cv;
        cv.x = (c == 0 && g == 0) ? v.x : __cosf(v.x);  // channel 0 linear, rest cos
        cv.y = __cosf(v.y);
        f32x2 f = cv + (nw * dc + nb);                  // pk_fma + pk_add
        ss = fmaf(f.x, f.x, ss);
        ss = fmaf(f.y, f.y, ss);
        fp[g] = f;
    }
    ss += __shfl_xor(ss, 1, 4);
    ss += __shfl_xor(ss, 2, 4);
    const float inv = 1.0f / fmaxf(sqrtf(ss), 1e-12f);
    unsigned pk[8];
    #pragma unroll
    for (int g = 0; g < 8; ++g)
        pk[g] = pack2bf(fp[g].x * inv, fp[g].y * inv);  // v_cvt_pk_bf16_f32
    uint4 v0 = make_uint4(pk[0], pk[1], pk[2], pk[3]);
    uint4 v1 = make_uint4(pk[4], pk[5], pk[6], pk[7]);
    ((uint4*)dstA)[0] = v0; ((uint4*)dstA)[1] = v1;
    if (dstC) { ((uint4*)dstC)[0] = v0; ((uint4*)dstC)[1] = v1; }
}

template<int FMODE, bool USE_WS>
__device__ __forceinline__ void body(
    Smem& sm,
    const void* dt_node, const void* deg_node, const void* cc_node,
    const void* dt_neigh, const void* deg_neigh, const void* cc_neigh,
    const void* neigh_mask, const void* feature_hist,
    const void* t2v_w, const void* t2v_b, const void* node_w, const void* node_b,
    const void* att_W1, const void* att_W2, const void* att_v,
    const void* weight, void* out, const void* ws, int mmode, int b0, int tid)
{
    const int lane = tid & 63;
    const int wv   = tid >> 6;
    const int m16  = lane & 15;
    const int quad = lane >> 4;

    // ---- Phase 0: stage params into LDS (1 load/thread; wave-uniform branch) ----
    {
        const int arr = tid >> 6, ch = tid & 63;
        float v;
        if      (arr == 0) v = LD<FMODE>(t2v_w,  ch);
        else if (arr == 1) v = LD<FMODE>(t2v_b,  ch);
        else if (arr == 2) v = LD<FMODE>(node_w, ch);
        else               v = 2.0f * LD<FMODE>(node_b, ch);   // deg-bias + cc-bias folded
        sm.prm[arr][ch] = v;
    }
    __syncthreads();

    // ---- Phase 1: features. 1040 tasks = (4 rows x 65 feat-rows) x 4 chunks ----
    {
        const int c = tid & 3, d0 = c * 16;               // chunk invariant across iterations
        const float* sw  = sm.prm[0] + d0;
        const float* sb  = sm.prm[1] + d0;
        const float* snw = sm.prm[2] + d0;
        const float* snb = sm.prm[3] + d0;

        #pragma unroll
        for (int it = 0; it < 5; ++it) {
            const int t = tid + it * 256;
            if (t < R_PB * 65 * 4) {
                const int f = t >> 2;
                if (f < R_PB * 64) {
                    const int row = f >> 6, n = f & 63;
                    const int idx = (b0 + row) * N_SZ + n;
                    const float tn  = fabsf(LD<FMODE>(dt_neigh, idx));
                    const float dcn = LD<FMODE>(deg_neigh, idx) + LD<FMODE>(cc_neigh, idx);
                    feat_row(tn, dcn, sw, sb, snw, snb, c,
                             sm.A + (row * 65 + n) * ARS + d0, nullptr);
                } else {
                    const int row = f - R_PB * 64;
                    const float tn = fabsf(LD<FMODE>(dt_node, b0 + row));
                    const float dc = LD<FMODE>(deg_node, b0 + row) + LD<FMODE>(cc_node, b0 + row);
                    feat_row(tn, dc, sw, sb, snw, snb, c,
                             sm.A + (row * 65 + 64) * ARS + d0,
                             sm.comb + row * CRS + d0);
                }
            }
        }
    }
    __syncthreads();

    // ---- Phase 2: S + att for row r = wv (wave-private to the end of phase 4) ----
    // S[m][e] = node@W1[e] (identical rows -> once per e-tile) + neigh[m]@W2[e]
    {
        const int r = wv;
        const unsigned short* An = sm.A + (r * 65 + 64) * ARS + quad * 8;
        const bf16x8 a0 = *(const bf16x8*)An;          // node k  0..31
        const bf16x8 a1 = *(const bf16x8*)(An + 32);   // node k 32..63
        const bf16x8* wfrag = (const bf16x8*)ws;

        f32x4  accN[4];
        bf16x8 w2f[4], w3f[4];
        float  ve[4];
        #pragma unroll
        for (int et = 0; et < 4; ++et) {
            bf16x8 w0, w1;
            if constexpr (USE_WS) {
                w0      = wfrag[(et * 4 + 0) * 64 + lane];
                w1      = wfrag[(et * 4 + 1) * 64 + lane];
                w2f[et] = wfrag[(et * 4 + 2) * 64 + lane];
                w3f[et] = wfrag[(et * 4 + 3) * 64 + lane];
            } else {
                const int col = et * 16 + m16;
                #pragma unroll
                for (int j = 0; j < 8; ++j) {
                    const int k0 = quad * 8 + j;
                    if constexpr (FMODE == 0) {
                        w0[j]      = (short)((const unsigned short*)att_W1)[k0 * D_SZ + col];
                        w1[j]      = (short)((const unsigned short*)att_W1)[(k0 + 32) * D_SZ + col];
                        w2f[et][j] = (short)((const unsigned short*)att_W2)[k0 * D_SZ + col];
                        w3f[et][j] = (short)((const unsigned short*)att_W2)[(k0 + 32) * D_SZ + col];
                    } else {
                        w0[j]      = (short)f2bfbits(((const float*)att_W1)[k0 * D_SZ + col]);
                        w1[j]      = (short)f2bfbits(((const float*)att_W1)[(k0 + 32) * D_SZ + col]);
                        w2f[et][j] = (short)f2bfbits(((const float*)att_W2)[k0 * D_SZ + col]);
                        w3f[et][j] = (short)f2bfbits(((const float*)att_W2)[(k0 + 32) * D_SZ + col]);
                    }
                }
            }
            f32x4 z = {0.f, 0.f, 0.f, 0.f};
            z = __builtin_amdgcn_mfma_f32_16x16x32_bf16(a0, w0, z, 0, 0, 0);
            z = __builtin_amdgcn_mfma_f32_16x16x32_bf16(a1, w1, z, 0, 0, 0);
            accN[et] = z;
            ve[et]   = LD<FMODE>(att_v, et * 16 + m16);
        }

        #pragma unroll
        for (int mt = 0; mt < 4; ++mt) {
            const unsigned short* Ar = sm.A + (r * 65 + mt * 16 + m16) * ARS + quad * 8;
            const bf16x8 a2 = *(const bf16x8*)Ar;          // neigh k  0..31
            const bf16x8 a3 = *(const bf16x8*)(Ar + 32);   // neigh k 32..63
            float p0 = 0.f, p1 = 0.f, p2 = 0.f, p3 = 0.f;
            #pragma unroll
            for (int et = 0; et < 4; ++et) {
                f32x4 acc = __builtin_amdgcn_mfma_f32_16x16x32_bf16(a2, w2f[et], accN[et], 0, 0, 0);
                acc       = __builtin_amdgcn_mfma_f32_16x16x32_bf16(a3, w3f[et], acc,      0, 0, 0);
                p0 = fmaf(tanh_fast(acc[0]), ve[et], p0);
                p1 = fmaf(tanh_fast(acc[1]), ve[et], p1);
                p2 = fmaf(tanh_fast(acc[2]), ve[et], p2);
                p3 = fmaf(tanh_fast(acc[3]), ve[et], p3);
            }
            p0 = dpp_add<0xB1>(p0); p0 = dpp_add<0x4E>(p0); p0 = dpp_add<0x124>(p0); p0 = dpp_add<0x128>(p0);
            p1 = dpp_add<0xB1>(p1); p1 = dpp_add<0x4E>(p1); p1 = dpp_add<0x124>(p1); p1 = dpp_add<0x128>(p1);
            p2 = dpp_add<0xB1>(p2); p2 = dpp_add<0x4E>(p2); p2 = dpp_add<0x124>(p2); p2 = dpp_add<0x128>(p2);
            p3 = dpp_add<0xB1>(p3); p3 = dpp_add<0x4E>(p3); p3 = dpp_add<0x124>(p3); p3 = dpp_add<0x128>(p3);
            if (m16 == 0) {
                sm.att[r][mt * 16 + quad * 4 + 0] = p0;
                sm.att[r][mt * 16 + quad * 4 + 1] = p1;
                sm.att[r][mt * 16 + quad * 4 + 2] = p2;
                sm.att[r][mt * 16 + quad * 4 + 3] = p3;
            }
        }
    }

    // ---- Phase 3: scores -> wn; feature_hist -> comb (wave-private, same wave as P2) ----
    {
        const int r   = wv;
        const int idx = (b0 + r) * N_SZ + lane;
        const float dt = LD<FMODE>(dt_neigh, idx);
        const float ts = 1.0f / fmaf(2.0f, dt, 1.0f);   // Decayer(2,'rev')
        const float lr = ts >= 0.0f ? ts : 0.01f * ts;  // leaky_relu
        const float m  = mval(neigh_mask, idx, mmode);
        float cnt = m;
        #pragma unroll
        for (int off = 32; off > 0; off >>= 1) cnt += __shfl_down(cnt, off, 64);
        cnt = __shfl(cnt, 0, 64);
        sm.wn[r][lane] = m * lr * sm.att[r][lane] / fmaxf(cnt, 1.0f);

        if constexpr (FMODE == 0) {
            const unsigned u = ((const unsigned*)feature_hist)[(b0 + r) * 64 + lane];
            *(unsigned*)(sm.comb + r * CRS + 2 * D_SZ + 2 * lane) = u;
        } else {
            const float* fh = (const float*)feature_hist + (b0 + r) * 2 * D_SZ + 2 * lane;
            *(unsigned*)(sm.comb + r * CRS + 2 * D_SZ + 2 * lane) = pack2bf(fh[0], fh[1]);
        }
    }

    // ---- Phase 4: neigh_agg (wave-private; lane = d; 4 partial accs break the fma chain) ----
    {
        const int r = wv;
        float g0 = 0.f, g1 = 0.f, g2 = 0.f, g3 = 0.f;
        #pragma unroll
        for (int n = 0; n < N_SZ; n += 4) {
            g0 = fmaf(sm.wn[r][n + 0], bits2f(sm.A[(r * 65 + n + 0) * ARS + lane]), g0);
            g1 = fmaf(sm.wn[r][n + 1], bits2f(sm.A[(r * 65 + n + 1) * ARS + lane]), g1);
            g2 = fmaf(sm.wn[r][n + 2], bits2f(sm.A[(r * 65 + n + 2) * ARS + lane]), g2);
            g3 = fmaf(sm.wn[r][n + 3], bits2f(sm.A[(r * 65 + n + 3) * ARS + lane]), g3);
        }
        const float agg = (g0 + g1) + (g2 + g3);
        sm.comb[r * CRS + D_SZ + lane] = (unsigned short)f2bfbits(agg);
    }
    __syncthreads();

    // ---- Phase 5: GEMV via MFMA. A rows = comb[m16&3] (duplicated), N=128 h, K=256 ----
    {
        bf16x8 AF[8];
        #pragma unroll
        for (int ks = 0; ks < 8; ++ks)
            AF[ks] = *(const bf16x8*)(sm.comb + (m16 & 3) * CRS + ks * 32 + quad * 8);
        #pragma unroll
        for (int t2 = 0; t2 < 2; ++t2) {
            const int nt = wv * 2 + t2;
            f32x4 c = {0.f, 0.f, 0.f, 0.f};
            #pragma unroll
            for (int ks = 0; ks < 8; ++ks) {
                bf16x8 bw;
                if constexpr (FMODE == 0) {
                    bw = *(const bf16x8*)((const unsigned short*)weight
                            + (nt * 16 + m16) * (4 * D_SZ) + ks * 32 + quad * 8);
                } else {
                    const float* wr = (const float*)weight
                            + (nt * 16 + m16) * (4 * D_SZ) + ks * 32 + quad * 8;
                    #pragma unroll
                    for (int j = 0; j < 8; ++j) bw[j] = (short)f2bfbits(wr[j]);
                }
                c = __builtin_amdgcn_mfma_f32_16x16x32_bf16(AF[ks], bw, c, 0, 0, 0);
            }
            if (quad == 0) {   // C rows 0..3 = quad 0, regs 0..3; col = m16
                #pragma unroll
                for (int rr = 0; rr < R_PB; ++rr) {
                    const float v = fmaxf(c[rr], 0.0f);
                    if constexpr (FMODE == 0)
                        ((__hip_bfloat16*)out)[(b0 + rr) * H_SZ + nt * 16 + m16] = __float2bfloat16(v);
                    else
                        ((float*)out)[(b0 + rr) * H_SZ + nt * 16 + m16] = v;
                }
            }
        }
    }
}

template<bool USE_WS>
__global__ __launch_bounds__(256, 4) void fused_model_kernel(
    const void* dt_node, const void* deg_node, const void* cc_node,
    const void* dt_neigh, const void* deg_neigh, const void* cc_neigh,
    const void* neigh_mask, const void* feature_hist,
    const void* t2v_w, const void* t2v_b, const void* node_w, const void* node_b,
    const void* att_W1, const void* att_W2, const void* att_v,
    const void* weight, void* out, const void* ws)
{
    __shared__ Smem sm;
    const int b0  = blockIdx.x * R_PB;
    const int tid = threadIdx.x;

    // wave-uniform dtype detection on head bytes (no LDS, no barrier)
    const int fmode = __builtin_amdgcn_readfirstlane(detect_f32(dt_node));
    const int mmode = __builtin_amdgcn_readfirstlane(detect_mask_mode(neigh_mask));

    if (fmode == 0)
        body<0, USE_WS>(sm, dt_node, deg_node, cc_node, dt_neigh, deg_neigh, cc_neigh,
                        neigh_mask, feature_hist, t2v_w, t2v_b, node_w, node_b,
                        att_W1, att_W2, att_v, weight, out, ws, mmode, b0, tid);
    else
        body<1, USE_WS>(sm, dt_node, deg_node, cc_node, dt_neigh, deg_neigh, cc_neigh,
                        neigh_mask, feature_hist, t2v_w, t2v_b, node_w, node_b,
                        att_W1, att_W2, att_v, weight, out, ws, mmode, b0, tid);
}

extern "C" void kernel_launch(void* const* d_in, const int* in_sizes, int n_in,
                              void* d_out, int out_size, void* d_ws, size_t ws_size,
                              hipStream_t stream) {
    const bool use_ws = (ws_size >= 16384) && (d_ws != nullptr);
    if (use_ws) {
        prep_kernel<<<4, 256, 0, stream>>>(d_in[0], d_in[12], d_in[13], d_ws);
        fused_model_kernel<true><<<B_SZ / R_PB, 256, 0, stream>>>(
            d_in[0], d_in[1], d_in[2], d_in[3], d_in[4], d_in[5], d_in[6], d_in[7],
            d_in[8], d_in[9], d_in[10], d_in[11], d_in[12], d_in[13], d_in[14], d_in[15],
            d_out, d_ws);
    } else {
        fused_model_kernel<false><<<B_SZ / R_PB, 256, 0, stream>>>(
            d_in[0], d_in[1], d_in[2], d_in[3], d_in[4], d_in[5], d_in[6], d_in[7],
            d_in[8], d_in[9], d_in[10], d_in[11], d_in[12], d_in[13], d_in[14], d_in[15],
            d_out, d_ws);
    }
}